// Round 10
// baseline (325.250 us; speedup 1.0000x reference)
//
#include <hip/hip_runtime.h>

static constexpr int B_ = 256;
static constexpr int R_ = 1152;
static constexpr int C_ = 10;
static constexpr int O_ = 16;
static constexpr int I_ = 8;
static constexpr int SCO = C_ * O_;   // 160
static constexpr int NV = B_ * SCO;   // 40960

static constexpr int KS_NSEG = 128, KS_RT = 9;   // k_s: 128 segs x 9 r
static constexpr int KA_NSEG = 192, KA_RT = 6;   // k_a: 192 segs x 6 r
static constexpr int KA_GRID = KA_NSEG * 4;      // 768

// ---------------------------------------------------------------------------
// k_s (round-7 exact): partial[seg][co][b] = sum_{r in seg} c * (W . x)
// Block = (seg, bq, ch): 64 b x 80 co x 9 r. bl=t&15 -> 4 b, grp=t>>4 -> 5 co.
// Stores fully line-coalesced (16 lanes x 16B contiguous); LDS stride-16
// 2-way aliasing (free). grid = 128*8 = 1024, XCD-swizzled on seg.
// ---------------------------------------------------------------------------
__global__ __launch_bounds__(256, 4) void k_s(const float* __restrict__ x,
                                              const float* __restrict__ W,
                                              const float* __restrict__ cvec,
                                              float* __restrict__ partial,
                                              int use_c) {
  __shared__ float sx[KS_RT * 8 * 68];
  const int bx  = blockIdx.x;
  const int seg = ((bx >> 6) << 3) | (bx & 7);
  const int sub = (bx >> 3) & 7;
  const int bq = sub >> 1;
  const int ch = sub & 1;
  const int t  = threadIdx.x;
  const int bl  = t & 15;
  const int grp = t >> 4;
  const int b0  = bq * 64 + bl * 4;
  const int co0 = ch * 80 + grp * 5;
  const int rbase = seg * KS_RT;
  for (int idx = t; idx < 64 * KS_RT * 2; idx += 256) {
    const int b = idx / (KS_RT * 2), f4 = idx - b * (KS_RT * 2);
    const float4 val = *(const float4*)(x + (size_t)(bq * 64 + b) * (R_ * I_)
                                          + rbase * I_ + f4 * 4);
    const int rr = f4 >> 1, i4 = (f4 & 1) * 4;
    sx[(rr * 8 + i4 + 0) * 68 + b] = val.x;
    sx[(rr * 8 + i4 + 1) * 68 + b] = val.y;
    sx[(rr * 8 + i4 + 2) * 68 + b] = val.z;
    sx[(rr * 8 + i4 + 3) * 68 + b] = val.w;
  }
  __syncthreads();
  const int cA = co0 >> 4, cB = (co0 + 4) >> 4;
  bool selB[5];
#pragma unroll
  for (int j = 0; j < 5; ++j) selB[j] = ((co0 + j) >> 4) != cA;
  float acc[4][5];
#pragma unroll
  for (int bb = 0; bb < 4; ++bb)
#pragma unroll
    for (int j = 0; j < 5; ++j) acc[bb][j] = 0.0f;
  for (int rr = 0; rr < KS_RT; ++rr) {
    const int r = rbase + rr;
    float4 wf[10];
    const float4* wp = (const float4*)(W + (size_t)r * 1280 + co0 * 8);
#pragma unroll
    for (int q = 0; q < 10; ++q) wf[q] = wp[q];
    const float cwA = use_c ? cvec[r * C_ + cA] : (1.0f / 1152.0f);
    const float cwB = use_c ? cvec[r * C_ + cB] : (1.0f / 1152.0f);
    float4 xv[8];
#pragma unroll
    for (int i = 0; i < 8; ++i)
      xv[i] = *(const float4*)(sx + (rr * 8 + i) * 68 + bl * 4);
    const float* xr = (const float*)xv;
#pragma unroll
    for (int j = 0; j < 5; ++j) {
      const float cw = selB[j] ? cwB : cwA;
      const float* wj = (const float*)&wf[j * 2];
#pragma unroll
      for (int bb = 0; bb < 4; ++bb) {
        float d = wj[0] * xr[bb];
        d = fmaf(wj[1], xr[4 + bb], d);  d = fmaf(wj[2], xr[8 + bb], d);
        d = fmaf(wj[3], xr[12 + bb], d); d = fmaf(wj[4], xr[16 + bb], d);
        d = fmaf(wj[5], xr[20 + bb], d); d = fmaf(wj[6], xr[24 + bb], d);
        d = fmaf(wj[7], xr[28 + bb], d);
        acc[bb][j] = fmaf(cw, d, acc[bb][j]);
      }
    }
  }
  float* pp = partial + (size_t)seg * NV + (size_t)co0 * 256 + b0;
#pragma unroll
  for (int j = 0; j < 5; ++j)
    *(float4*)(pp + j * 256) = make_float4(acc[0][j], acc[1][j], acc[2][j], acc[3][j]);
}

// ---------------------------------------------------------------------------
// k_sv: s = sum over 128 partials; squash v = s*|s|/(1+s^2)
// grid 640: block covers 64 elems; thread sums 32 segs; 4-way LDS combine.
// Also zeroes the k_a last-block counter (runs before k_a in-stream).
// ---------------------------------------------------------------------------
__global__ __launch_bounds__(256) void k_sv(const float* __restrict__ partial,
                                            float* __restrict__ dst, int direct,
                                            int* __restrict__ cnt) {
  __shared__ float red[4][64];
  const int t = threadIdx.x;
  if (blockIdx.x == 0 && t == 0) *cnt = 0;
  const int e = t & 63, q = t >> 6;
  const int i = blockIdx.x * 64 + e;            // i = co*256 + b
  const float* p = partial + (size_t)(q * 32) * NV + i;
  float s = 0.0f;
#pragma unroll 8
  for (int g = 0; g < 32; ++g) s += p[(size_t)g * NV];
  red[q][e] = s;
  __syncthreads();
  if (t < 64) {
    const int ii = blockIdx.x * 64 + t;
    const float ss = red[0][t] + red[1][t] + red[2][t] + red[3][t];
    const float val = ss * fabsf(ss) / (1.0f + ss * ss);
    if (direct) dst[(ii & 255) * SCO + (ii >> 8)] = val;  // out[b][co]
    else        dst[ii] = val;                            // v[co][b]
  }
}

// ---------------------------------------------------------------------------
// k_a (round-7 exact) + fused k_bc tail via last-block pattern:
// bpart[bq][r][c] = sum_{b in bq} sum_o (W . x) * v ; the last block to
// finish (atomic ticket) computes b-update + softmax for all 10 c.
// grid = 192*4 = 768, XCD-swizzled on seg.
// ---------------------------------------------------------------------------
__global__ __launch_bounds__(256, 3) void k_a(const float* __restrict__ x,
                                              const float* __restrict__ W,
                                              const float* __restrict__ v,
                                              float* __restrict__ bpart,
                                              float* __restrict__ bvec,
                                              float* __restrict__ cvec,
                                              int* __restrict__ cnt, int first) {
  __shared__ float sx[KA_RT * 8 * 68];
  __shared__ float red[KA_RT][16][10];
  __shared__ float smx[4];
  __shared__ float sms[4];
  __shared__ int lastflag;
  const int bx  = blockIdx.x;
  const int seg = ((bx >> 5) << 3) | (bx & 7);
  const int bq  = (bx >> 3) & 3;
  const int t   = threadIdx.x;
  const int bl  = t & 15;
  const int grp = t >> 4;
  const int b0  = bq * 64 + bl * 4;
  const int rbase = seg * KA_RT;
  for (int idx = t; idx < 64 * KA_RT * 2; idx += 256) {
    const int b = idx / (KA_RT * 2), f4 = idx - b * (KA_RT * 2);
    const float4 val = *(const float4*)(x + (size_t)(bq * 64 + b) * (R_ * I_)
                                          + rbase * I_ + f4 * 4);
    const int rr = f4 >> 1, i4 = (f4 & 1) * 4;
    sx[(rr * 8 + i4 + 0) * 68 + b] = val.x;
    sx[(rr * 8 + i4 + 1) * 68 + b] = val.y;
    sx[(rr * 8 + i4 + 2) * 68 + b] = val.z;
    sx[(rr * 8 + i4 + 3) * 68 + b] = val.w;
  }
  float4 vf[10];
#pragma unroll
  for (int j = 0; j < 10; ++j)
    vf[j] = *(const float4*)(v + (size_t)(j * 16 + grp) * 256 + b0);
  __syncthreads();
  for (int rr = 0; rr < KA_RT; ++rr) {
    const int r = rbase + rr;
    float4 xv[8];
#pragma unroll
    for (int i = 0; i < 8; ++i)
      xv[i] = *(const float4*)(sx + (rr * 8 + i) * 68 + bl * 4);
    const float* xr = (const float*)xv;
    float p[10];
#pragma unroll
    for (int j = 0; j < 10; ++j) {
      const float* wj = W + (size_t)((r * C_ + j) * O_ + grp) * I_;
      const float4 w0 = *(const float4*)wj, w1 = *(const float4*)(wj + 4);
      const float* vfj = (const float*)&vf[j];
      float a = 0.0f;
#pragma unroll
      for (int bb = 0; bb < 4; ++bb) {
        float d = w0.x * xr[bb];
        d = fmaf(w0.y, xr[4 + bb], d);  d = fmaf(w0.z, xr[8 + bb], d);
        d = fmaf(w0.w, xr[12 + bb], d); d = fmaf(w1.x, xr[16 + bb], d);
        d = fmaf(w1.y, xr[20 + bb], d); d = fmaf(w1.z, xr[24 + bb], d);
        d = fmaf(w1.w, xr[28 + bb], d);
        a = fmaf(d, vfj[bb], a);
      }
      p[j] = a;
    }
#pragma unroll
    for (int j = 0; j < 10; ++j) {
      float a = p[j];
      a += __shfl_xor(a, 1); a += __shfl_xor(a, 2);
      a += __shfl_xor(a, 4); a += __shfl_xor(a, 8);
      p[j] = a;
    }
    if (bl == 0) {
#pragma unroll
      for (int j = 0; j < 10; ++j) red[rr][grp][j] = p[j];
    }
  }
  __syncthreads();
  if (t < KA_RT * 10) {
    const int rr = t / 10, c = t - rr * 10;
    float s = 0.0f;
#pragma unroll
    for (int g = 0; g < 16; ++g) s += red[rr][g][c];
    bpart[((size_t)bq * R_ + (rbase + rr)) * C_ + c] = s;
  }

  // ---- last-block fused k_bc (device-scope fence + atomic ticket) ----
  __threadfence();
  __syncthreads();
  if (t == 0) lastflag = (atomicAdd(cnt, 1) == KA_GRID - 1) ? 1 : 0;
  __syncthreads();
  if (!lastflag) return;
  __threadfence();   // acquire: make all blocks' bpart stores visible

  for (int c = 0; c < C_; ++c) {
    float bv[5], ef[5];
    float mx = -3.402823466e38f;
#pragma unroll
    for (int k = 0; k < 5; ++k) {
      int r = t + k * 256;
      if (r < R_) {
        float s = bpart[(size_t)r * C_ + c]
                + bpart[((size_t)R_ + r) * C_ + c]
                + bpart[((size_t)2 * R_ + r) * C_ + c]
                + bpart[((size_t)3 * R_ + r) * C_ + c];
        float val = s * (1.0f / 256.0f);
        if (!first) val += bvec[r * C_ + c];
        bvec[r * C_ + c] = val;
        bv[k] = val;
        mx = fmaxf(mx, val);
      }
    }
    mx = fmaxf(mx, __shfl_xor(mx, 1));  mx = fmaxf(mx, __shfl_xor(mx, 2));
    mx = fmaxf(mx, __shfl_xor(mx, 4));  mx = fmaxf(mx, __shfl_xor(mx, 8));
    mx = fmaxf(mx, __shfl_xor(mx, 16)); mx = fmaxf(mx, __shfl_xor(mx, 32));
    if ((t & 63) == 0) smx[t >> 6] = mx;
    __syncthreads();
    const float MX = fmaxf(fmaxf(smx[0], smx[1]), fmaxf(smx[2], smx[3]));
    float se = 0.0f;
#pragma unroll
    for (int k = 0; k < 5; ++k) {
      int r = t + k * 256;
      if (r < R_) { ef[k] = expf(bv[k] - MX); se += ef[k]; }
    }
    se += __shfl_xor(se, 1);  se += __shfl_xor(se, 2);  se += __shfl_xor(se, 4);
    se += __shfl_xor(se, 8);  se += __shfl_xor(se, 16); se += __shfl_xor(se, 32);
    if ((t & 63) == 0) sms[t >> 6] = se;
    __syncthreads();
    const float inv = 1.0f / ((sms[0] + sms[1]) + (sms[2] + sms[3]));
#pragma unroll
    for (int k = 0; k < 5; ++k) {
      int r = t + k * 256;
      if (r < R_) cvec[r * C_ + c] = ef[k] * inv;
    }
    __syncthreads();
  }
}

extern "C" void kernel_launch(void* const* d_in, const int* in_sizes, int n_in,
                              void* d_out, int out_size, void* d_ws, size_t ws_size,
                              hipStream_t stream) {
  const float* x = (const float*)d_in[0];  // (B,R,I) fp32
  const float* W = (const float*)d_in[1];  // (R,C,O,I) fp32
  float* out = (float*)d_out;              // (B,C,O,1) fp32
  float* ws = (float*)d_ws;

  float* partial = ws;                             // 128 * NV
  float* v     = partial + (size_t)KS_NSEG * NV;   // NV, layout [co][b]
  float* bvec  = v + NV;
  float* cvec  = bvec + (R_ * C_);
  float* bpart = cvec + (R_ * C_);                 // 4 * R * C
  int*   cnt   = (int*)(bpart + 4 * R_ * C_);      // last-block ticket

  for (int it = 0; it < 3; ++it) {
    k_s<<<KS_NSEG * 8, 256, 0, stream>>>(x, W, cvec, partial, it > 0 ? 1 : 0);
    k_sv<<<NV / 64, 256, 0, stream>>>(partial, (it == 2) ? out : v,
                                      it == 2 ? 1 : 0, cnt);
    if (it < 2) {
      k_a<<<KA_GRID, 256, 0, stream>>>(x, W, v, bpart, bvec, cvec, cnt,
                                       it == 0 ? 1 : 0);
    }
  }
}

// Round 11
// 223.886 us; speedup vs baseline: 1.4527x; 1.4527x over previous
//
#include <hip/hip_runtime.h>

static constexpr int B_ = 256;
static constexpr int R_ = 1152;
static constexpr int C_ = 10;
static constexpr int O_ = 16;
static constexpr int I_ = 8;
static constexpr int SCO = C_ * O_;   // 160
static constexpr int NV = B_ * SCO;   // 40960
static constexpr int K_ = R_ * I_;    // 9216

static constexpr int GEMM_KS = 16;               // K-split
static constexpr int KC = K_ / GEMM_KS;          // 576 (72 r)
static constexpr int KA_NSEG = 192, KA_RT = 6;   // k_a: 192 segs x 6 r

typedef short bf16x8 __attribute__((ext_vector_type(8)));
typedef float f32x4  __attribute__((ext_vector_type(4)));

__device__ __forceinline__ unsigned short f2bf(float f) {
  union { float f; unsigned int u; } c; c.f = f;
  const unsigned int u = c.u;
  return (unsigned short)((u + 0x7fffu + ((u >> 16) & 1u)) >> 16);  // RNE
}

// ---------------------------------------------------------------------------
// prep0: xb[b][k] = bf16(x), wcb[co][k] = bf16((1/1152) * W[r,c,o,i]), k=r*8+i
// blocks 0..159: (c = bx/16, rt = bx%16) -> Wcb slice. blocks 160..169: xb.
// ---------------------------------------------------------------------------
__global__ __launch_bounds__(256) void prep0(const float* __restrict__ x,
                                             const float* __restrict__ W,
                                             unsigned short* __restrict__ xb,
                                             unsigned short* __restrict__ wcb) {
  const int bx = blockIdx.x;
  const int t  = threadIdx.x;
  if (bx < 160) {
    const int c = bx >> 4, rt = bx & 15;       // 72 r per slice
    for (int idx = t; idx < 16 * 72 * 8; idx += 256) {
      const int o = idx / 576, rem = idx - o * 576;
      const int r = rt * 72 + (rem >> 3), i = rem & 7;
      const float wv = W[(size_t)r * 1280 + c * 128 + o * 8 + i];
      wcb[(size_t)(c * 16 + o) * K_ + r * 8 + i] = f2bf(wv * (1.0f / 1152.0f));
    }
  } else {
    const float4* xf = (const float4*)x;
    ushort4* xo = (ushort4*)xb;
    for (int idx = (bx - 160) * 256 + t; idx < (B_ * K_) / 4; idx += 2560) {
      const float4 v4 = xf[idx];
      ushort4 o4;
      o4.x = f2bf(v4.x); o4.y = f2bf(v4.y); o4.z = f2bf(v4.z); o4.w = f2bf(v4.w);
      xo[idx] = o4;
    }
  }
}

// ---------------------------------------------------------------------------
// k_gemm: partial[ks][co][b] = X(256x9216) . Wc(9216x160), K-chunk per block.
// MFMA 16x16x32 bf16, direct global fragment loads (A: x row-major [b][k];
// B: Wc [co][k] -> B[k][n] frag, n=lane&15, k=quad*8+j). C LDS-transposed
// to coalesced float4 stores. grid = 640 (4 btile x 10 cotile x 16 ks).
// ---------------------------------------------------------------------------
__global__ __launch_bounds__(256, 4) void k_gemm(const unsigned short* __restrict__ xb,
                                                 const unsigned short* __restrict__ wcb,
                                                 float* __restrict__ partial) {
  __shared__ float sx[16 * 68];
  const int bx = blockIdx.x;
  const int xcd = bx & 7, idx = bx >> 3;        // same (btile,ks) -> same XCD
  const int cotile = idx % 10;
  const int g = xcd * 8 + idx / 10;             // 0..63
  const int btile = g >> 4, ks = g & 15;
  const int t = threadIdx.x, lane = t & 63;
  const int w = __builtin_amdgcn_readfirstlane(t >> 6);
  const int m0 = btile * 64 + w * 16;
  const int n0 = cotile * 16;
  const int kbase = ks * KC;
  const int mrow = lane & 15, quad = lane >> 4;

  const unsigned short* ap = xb  + (size_t)(m0 + mrow) * K_ + kbase + quad * 8;
  const unsigned short* bp = wcb + (size_t)(n0 + mrow) * K_ + kbase + quad * 8;
  f32x4 acc = {0.0f, 0.0f, 0.0f, 0.0f};
#pragma unroll
  for (int kk = 0; kk < KC / 32; ++kk) {        // 18 MFMAs
    const bf16x8 a = *(const bf16x8*)(ap + kk * 32);
    const bf16x8 b = *(const bf16x8*)(bp + kk * 32);
    acc = __builtin_amdgcn_mfma_f32_16x16x32_bf16(a, b, acc, 0, 0, 0);
  }
  // C layout: n(col)=lane&15, m(row)=quad*4+reg  ->  LDS [n][m] (pad 68)
#pragma unroll
  for (int rg = 0; rg < 4; ++rg)
    sx[mrow * 68 + w * 16 + quad * 4 + rg] = acc[rg];
  __syncthreads();
  const int n = t >> 4, b4 = (t & 15) * 4;
  const float4 o = *(const float4*)&sx[n * 68 + b4];
  *(float4*)(partial + (size_t)ks * NV + (n0 + n) * 256 + btile * 64 + b4) = o;
}

// ---------------------------------------------------------------------------
// k_sv: s = sum over 16 partials; squash v = s*|s|/(1+s^2)  (division-safe,
// == s^3/((1+s^2)*sqrt(s^2))). v layout [co][b]; direct=1 -> out[b][co].
// ---------------------------------------------------------------------------
__global__ __launch_bounds__(256) void k_sv(const float* __restrict__ partial,
                                            float* __restrict__ dst, int direct) {
  const int i = blockIdx.x * 256 + threadIdx.x;  // i = co*256 + b
  float s = 0.0f;
#pragma unroll
  for (int g = 0; g < GEMM_KS; ++g) s += partial[(size_t)g * NV + i];
  const float val = s * fabsf(s) / (1.0f + s * s);
  if (direct) dst[(i & 255) * SCO + (i >> 8)] = val;
  else        dst[i] = val;
}

// ---------------------------------------------------------------------------
// k_a (round-7 exact, fp32): bpart[bq][r][c] = sum_{b in bq} sum_o u_hat * v
// grid = 192*4 = 768, XCD-swizzled on seg.
// ---------------------------------------------------------------------------
__global__ __launch_bounds__(256, 3) void k_a(const float* __restrict__ x,
                                              const float* __restrict__ W,
                                              const float* __restrict__ v,
                                              float* __restrict__ bpart) {
  __shared__ float sx[KA_RT * 8 * 68];
  __shared__ float red[KA_RT][16][10];
  const int bx  = blockIdx.x;
  const int seg = ((bx >> 5) << 3) | (bx & 7);
  const int bq  = (bx >> 3) & 3;
  const int t   = threadIdx.x;
  const int bl  = t & 15;
  const int grp = t >> 4;
  const int b0  = bq * 64 + bl * 4;
  const int rbase = seg * KA_RT;
  for (int idx = t; idx < 64 * KA_RT * 2; idx += 256) {
    const int b = idx / (KA_RT * 2), f4 = idx - b * (KA_RT * 2);
    const float4 val = *(const float4*)(x + (size_t)(bq * 64 + b) * (R_ * I_)
                                          + rbase * I_ + f4 * 4);
    const int rr = f4 >> 1, i4 = (f4 & 1) * 4;
    sx[(rr * 8 + i4 + 0) * 68 + b] = val.x;
    sx[(rr * 8 + i4 + 1) * 68 + b] = val.y;
    sx[(rr * 8 + i4 + 2) * 68 + b] = val.z;
    sx[(rr * 8 + i4 + 3) * 68 + b] = val.w;
  }
  float4 vf[10];
#pragma unroll
  for (int j = 0; j < 10; ++j)
    vf[j] = *(const float4*)(v + (size_t)(j * 16 + grp) * 256 + b0);
  __syncthreads();
  for (int rr = 0; rr < KA_RT; ++rr) {
    const int r = rbase + rr;
    float4 xv[8];
#pragma unroll
    for (int i = 0; i < 8; ++i)
      xv[i] = *(const float4*)(sx + (rr * 8 + i) * 68 + bl * 4);
    const float* xr = (const float*)xv;
    float p[10];
#pragma unroll
    for (int j = 0; j < 10; ++j) {
      const float* wj = W + (size_t)((r * C_ + j) * O_ + grp) * I_;
      const float4 w0 = *(const float4*)wj, w1 = *(const float4*)(wj + 4);
      const float* vfj = (const float*)&vf[j];
      float a = 0.0f;
#pragma unroll
      for (int bb = 0; bb < 4; ++bb) {
        float d = w0.x * xr[bb];
        d = fmaf(w0.y, xr[4 + bb], d);  d = fmaf(w0.z, xr[8 + bb], d);
        d = fmaf(w0.w, xr[12 + bb], d); d = fmaf(w1.x, xr[16 + bb], d);
        d = fmaf(w1.y, xr[20 + bb], d); d = fmaf(w1.z, xr[24 + bb], d);
        d = fmaf(w1.w, xr[28 + bb], d);
        a = fmaf(d, vfj[bb], a);
      }
      p[j] = a;
    }
#pragma unroll
    for (int j = 0; j < 10; ++j) {
      float a = p[j];
      a += __shfl_xor(a, 1); a += __shfl_xor(a, 2);
      a += __shfl_xor(a, 4); a += __shfl_xor(a, 8);
      p[j] = a;
    }
    if (bl == 0) {
#pragma unroll
      for (int j = 0; j < 10; ++j) red[rr][grp][j] = p[j];
    }
  }
  __syncthreads();
  if (t < KA_RT * 10) {
    const int rr = t / 10, c = t - rr * 10;
    float s = 0.0f;
#pragma unroll
    for (int g = 0; g < 16; ++g) s += red[rr][g][c];
    bpart[((size_t)bq * R_ + (rbase + rr)) * C_ + c] = s;
  }
}

// ---------------------------------------------------------------------------
// k_bc: grid 80 = (c, r-slice/8). Every block redundantly computes the full
// softmax for its c (reads bpart, 8x redundant — cheap); only rt==0 writes
// bvec_out (ping-pong, race-free). Tail: regenerate wcb[co][k] = bf16(c*W)
// for this block's (c, 144-r slice).
// ---------------------------------------------------------------------------
__global__ __launch_bounds__(256) void k_bc(const float* __restrict__ bpart,
                                            const float* __restrict__ bvec_in,
                                            float* __restrict__ bvec_out,
                                            const float* __restrict__ W,
                                            unsigned short* __restrict__ wcb,
                                            int first) {
  __shared__ float cl[R_];
  __shared__ float smx[4];
  __shared__ float sms[4];
  const int bx = blockIdx.x;
  const int c  = bx >> 3, rt = bx & 7;
  const int t  = threadIdx.x;
  float bv[5], ef[5];
  float mx = -3.402823466e38f;
#pragma unroll
  for (int k = 0; k < 5; ++k) {
    int r = t + k * 256;
    if (r < R_) {
      float s = bpart[(size_t)r * C_ + c]
              + bpart[((size_t)R_ + r) * C_ + c]
              + bpart[((size_t)2 * R_ + r) * C_ + c]
              + bpart[((size_t)3 * R_ + r) * C_ + c];
      float val = s * (1.0f / 256.0f);
      if (!first) val += bvec_in[r * C_ + c];
      if (rt == 0) bvec_out[r * C_ + c] = val;
      bv[k] = val;
      mx = fmaxf(mx, val);
    }
  }
  mx = fmaxf(mx, __shfl_xor(mx, 1));  mx = fmaxf(mx, __shfl_xor(mx, 2));
  mx = fmaxf(mx, __shfl_xor(mx, 4));  mx = fmaxf(mx, __shfl_xor(mx, 8));
  mx = fmaxf(mx, __shfl_xor(mx, 16)); mx = fmaxf(mx, __shfl_xor(mx, 32));
  if ((t & 63) == 0) smx[t >> 6] = mx;
  __syncthreads();
  const float MX = fmaxf(fmaxf(smx[0], smx[1]), fmaxf(smx[2], smx[3]));
  float se = 0.0f;
#pragma unroll
  for (int k = 0; k < 5; ++k) {
    int r = t + k * 256;
    if (r < R_) { ef[k] = expf(bv[k] - MX); se += ef[k]; }
  }
  se += __shfl_xor(se, 1);  se += __shfl_xor(se, 2);  se += __shfl_xor(se, 4);
  se += __shfl_xor(se, 8);  se += __shfl_xor(se, 16); se += __shfl_xor(se, 32);
  if ((t & 63) == 0) sms[t >> 6] = se;
  __syncthreads();
  const float inv = 1.0f / ((sms[0] + sms[1]) + (sms[2] + sms[3]));
#pragma unroll
  for (int k = 0; k < 5; ++k) {
    int r = t + k * 256;
    if (r < R_) cl[r] = ef[k] * inv;
  }
  __syncthreads();
  // regen Wcb for (c, r in [rt*144, rt*144+144))
  for (int idx = t; idx < 16 * 144 * 8; idx += 256) {
    const int o = idx / 1152, rem = idx - o * 1152;
    const int r = rt * 144 + (rem >> 3), i = rem & 7;
    const float wv = W[(size_t)r * 1280 + c * 128 + o * 8 + i];
    wcb[(size_t)(c * 16 + o) * K_ + r * 8 + i] = f2bf(wv * cl[r]);
  }
}

extern "C" void kernel_launch(void* const* d_in, const int* in_sizes, int n_in,
                              void* d_out, int out_size, void* d_ws, size_t ws_size,
                              hipStream_t stream) {
  const float* x = (const float*)d_in[0];  // (B,R,I) fp32
  const float* W = (const float*)d_in[1];  // (R,C,O,I) fp32
  float* out = (float*)d_out;              // (B,C,O,1) fp32
  float* ws = (float*)d_ws;

  float* partial = ws;                              // 16 * NV
  float* v      = partial + (size_t)GEMM_KS * NV;   // NV, [co][b]
  float* bvecA  = v + NV;
  float* bvecB  = bvecA + (R_ * C_);
  float* bpart  = bvecB + (R_ * C_);                // 4 * R * C
  unsigned short* xb  = (unsigned short*)(bpart + 4 * R_ * C_);  // B*K bf16
  unsigned short* wcb = xb + (size_t)B_ * K_;                    // 160*K bf16

  prep0<<<170, 256, 0, stream>>>(x, W, xb, wcb);
  for (int it = 0; it < 3; ++it) {
    k_gemm<<<640, 256, 0, stream>>>(xb, wcb, partial);
    k_sv<<<NV / 256, 256, 0, stream>>>(partial, (it == 2) ? out : v, it == 2 ? 1 : 0);
    if (it < 2) {
      k_a<<<KA_NSEG * 4, 256, 0, stream>>>(x, W, v, bpart);
      k_bc<<<80, 256, 0, stream>>>(bpart, bvecA, (it == 0) ? bvecA : bvecB,
                                   W, wcb, it == 0 ? 1 : 0);
    }
  }
}

// Round 12
// 174.480 us; speedup vs baseline: 1.8641x; 1.2832x over previous
//
#include <hip/hip_runtime.h>

static constexpr int B_ = 256;
static constexpr int R_ = 1152;
static constexpr int C_ = 10;
static constexpr int O_ = 16;
static constexpr int I_ = 8;
static constexpr int SCO = C_ * O_;   // 160
static constexpr int NV = B_ * SCO;   // 40960
static constexpr int K_ = R_ * I_;    // 9216

static constexpr int GEMM_KS = 16;               // K-split (72 r per chunk)
static constexpr int KA_NSEG = 192, KA_RT = 6;   // k_a: 192 segs x 6 r

typedef short bf16x8 __attribute__((ext_vector_type(8)));
typedef float f32x4  __attribute__((ext_vector_type(4)));

__device__ __forceinline__ unsigned short f2bf(float f) {
  union { float f; unsigned int u; } c; c.f = f;
  const unsigned int u = c.u;
  return (unsigned short)((u + 0x7fffu + ((u >> 16) & 1u)) >> 16);  // RNE
}

// ---------------------------------------------------------------------------
// prep0: pure element-wise, fully coalesced (no transpose).
//   wb[j] = bf16(W[j] / 1152)   (native [r][c][o][i] layout; iter-0 c weight)
//   xb[j] = bf16(x[j])          (native [b][r][i] = [b][k] layout)
// grid = 768: blocks 0..255 -> W (368640 f4), 256..767 -> x (589824 f4).
// ---------------------------------------------------------------------------
__global__ __launch_bounds__(256) void prep0(const float* __restrict__ x,
                                             const float* __restrict__ W,
                                             unsigned short* __restrict__ xb,
                                             unsigned short* __restrict__ wb) {
  const int bx = blockIdx.x;
  const int t  = threadIdx.x;
  if (bx < 256) {
    const float4* wf = (const float4*)W;
    ushort4* wo = (ushort4*)wb;
    for (int idx = bx * 256 + t; idx < (R_ * C_ * O_ * I_) / 4; idx += 65536) {
      const float4 v4 = wf[idx];
      ushort4 o4;
      o4.x = f2bf(v4.x * (1.0f / 1152.0f)); o4.y = f2bf(v4.y * (1.0f / 1152.0f));
      o4.z = f2bf(v4.z * (1.0f / 1152.0f)); o4.w = f2bf(v4.w * (1.0f / 1152.0f));
      wo[idx] = o4;
    }
  } else {
    const float4* xf = (const float4*)x;
    ushort4* xo = (ushort4*)xb;
    for (int idx = (bx - 256) * 256 + t; idx < (B_ * K_) / 4; idx += 131072) {
      const float4 v4 = xf[idx];
      ushort4 o4;
      o4.x = f2bf(v4.x); o4.y = f2bf(v4.y); o4.z = f2bf(v4.z); o4.w = f2bf(v4.w);
      xo[idx] = o4;
    }
  }
}

// ---------------------------------------------------------------------------
// k_gemm: partial[ks][co][b] = X(256x9216) . Wc(9216x160), K-chunk per block.
// MFMA 16x16x32 bf16. A: xb row-major [b][k], per-wave 16 rows x 64 B/kk.
// B: wb native [r][c][o][i] — lane(n=o) reads 16 B at r=r0+4kk+quad; a quad's
// 16 lanes are 256 B contiguous. C LDS-transposed to coalesced f4 stores.
// grid = 640 (4 btile x 10 c x 16 ks), XCD-swizzled.
// ---------------------------------------------------------------------------
__global__ __launch_bounds__(256, 4) void k_gemm(const unsigned short* __restrict__ xb,
                                                 const unsigned short* __restrict__ wb,
                                                 float* __restrict__ partial) {
  __shared__ float sx[16 * 68];
  const int bx = blockIdx.x;
  const int xcd = bx & 7, idx = bx >> 3;
  const int cotile = idx % 10;                  // = c
  const int g = xcd * 8 + idx / 10;             // 0..63
  const int btile = g >> 4, ks = g & 15;
  const int t = threadIdx.x, lane = t & 63;
  const int w = __builtin_amdgcn_readfirstlane(t >> 6);
  const int m0 = btile * 64 + w * 16;
  const int n0 = cotile * 16;
  const int mrow = lane & 15, quad = lane >> 4;

  const unsigned short* ap = xb + (size_t)(m0 + mrow) * K_ + ks * (K_ / GEMM_KS) + quad * 8;
  // B: r = ks*72 + kk*4 + quad, element base = ((r*C + c)*16 + o)*8, o = mrow
  const unsigned short* bp = wb + ((size_t)(ks * 72 + quad) * C_ + cotile) * 128 + mrow * 8;
  f32x4 acc = {0.0f, 0.0f, 0.0f, 0.0f};
#pragma unroll
  for (int kk = 0; kk < 18; ++kk) {             // 18 MFMAs, 72 r
    const bf16x8 a = *(const bf16x8*)(ap + kk * 32);
    const bf16x8 b = *(const bf16x8*)(bp + (size_t)kk * 4 * C_ * 128);
    acc = __builtin_amdgcn_mfma_f32_16x16x32_bf16(a, b, acc, 0, 0, 0);
  }
  // C layout: n(col)=lane&15, m(row)=quad*4+reg -> LDS [n][m] (pad 68)
#pragma unroll
  for (int rg = 0; rg < 4; ++rg)
    sx[mrow * 68 + w * 16 + quad * 4 + rg] = acc[rg];
  __syncthreads();
  const int n = t >> 4, b4 = (t & 15) * 4;
  const float4 o = *(const float4*)&sx[n * 68 + b4];
  *(float4*)(partial + (size_t)ks * NV + (n0 + n) * 256 + btile * 64 + b4) = o;
}

// ---------------------------------------------------------------------------
// k_sv: s = sum over 16 partials; squash v = s*|s|/(1+s^2)  (division-safe,
// == s^3/((1+s^2)*sqrt(s^2))). v layout [co][b]; direct=1 -> out[b][co].
// ---------------------------------------------------------------------------
__global__ __launch_bounds__(256) void k_sv(const float* __restrict__ partial,
                                            float* __restrict__ dst, int direct) {
  const int i = blockIdx.x * 256 + threadIdx.x;  // i = co*256 + b
  float s = 0.0f;
#pragma unroll
  for (int g = 0; g < GEMM_KS; ++g) s += partial[(size_t)g * NV + i];
  const float val = s * fabsf(s) / (1.0f + s * s);
  if (direct) dst[(i & 255) * SCO + (i >> 8)] = val;
  else        dst[i] = val;
}

// ---------------------------------------------------------------------------
// k_a (round-7 exact, fp32): bpart[bq][r][c] = sum_{b in bq} sum_o u_hat * v
// grid = 192*4 = 768, XCD-swizzled on seg.
// ---------------------------------------------------------------------------
__global__ __launch_bounds__(256, 3) void k_a(const float* __restrict__ x,
                                              const float* __restrict__ W,
                                              const float* __restrict__ v,
                                              float* __restrict__ bpart) {
  __shared__ float sx[KA_RT * 8 * 68];
  __shared__ float red[KA_RT][16][10];
  const int bx  = blockIdx.x;
  const int seg = ((bx >> 5) << 3) | (bx & 7);
  const int bq  = (bx >> 3) & 3;
  const int t   = threadIdx.x;
  const int bl  = t & 15;
  const int grp = t >> 4;
  const int b0  = bq * 64 + bl * 4;
  const int rbase = seg * KA_RT;
  for (int idx = t; idx < 64 * KA_RT * 2; idx += 256) {
    const int b = idx / (KA_RT * 2), f4 = idx - b * (KA_RT * 2);
    const float4 val = *(const float4*)(x + (size_t)(bq * 64 + b) * (R_ * I_)
                                          + rbase * I_ + f4 * 4);
    const int rr = f4 >> 1, i4 = (f4 & 1) * 4;
    sx[(rr * 8 + i4 + 0) * 68 + b] = val.x;
    sx[(rr * 8 + i4 + 1) * 68 + b] = val.y;
    sx[(rr * 8 + i4 + 2) * 68 + b] = val.z;
    sx[(rr * 8 + i4 + 3) * 68 + b] = val.w;
  }
  float4 vf[10];
#pragma unroll
  for (int j = 0; j < 10; ++j)
    vf[j] = *(const float4*)(v + (size_t)(j * 16 + grp) * 256 + b0);
  __syncthreads();
  for (int rr = 0; rr < KA_RT; ++rr) {
    const int r = rbase + rr;
    float4 xv[8];
#pragma unroll
    for (int i = 0; i < 8; ++i)
      xv[i] = *(const float4*)(sx + (rr * 8 + i) * 68 + bl * 4);
    const float* xr = (const float*)xv;
    float p[10];
#pragma unroll
    for (int j = 0; j < 10; ++j) {
      const float* wj = W + (size_t)((r * C_ + j) * O_ + grp) * I_;
      const float4 w0 = *(const float4*)wj, w1 = *(const float4*)(wj + 4);
      const float* vfj = (const float*)&vf[j];
      float a = 0.0f;
#pragma unroll
      for (int bb = 0; bb < 4; ++bb) {
        float d = w0.x * xr[bb];
        d = fmaf(w0.y, xr[4 + bb], d);  d = fmaf(w0.z, xr[8 + bb], d);
        d = fmaf(w0.w, xr[12 + bb], d); d = fmaf(w1.x, xr[16 + bb], d);
        d = fmaf(w1.y, xr[20 + bb], d); d = fmaf(w1.z, xr[24 + bb], d);
        d = fmaf(w1.w, xr[28 + bb], d);
        a = fmaf(d, vfj[bb], a);
      }
      p[j] = a;
    }
#pragma unroll
    for (int j = 0; j < 10; ++j) {
      float a = p[j];
      a += __shfl_xor(a, 1); a += __shfl_xor(a, 2);
      a += __shfl_xor(a, 4); a += __shfl_xor(a, 8);
      p[j] = a;
    }
    if (bl == 0) {
#pragma unroll
      for (int j = 0; j < 10; ++j) red[rr][grp][j] = p[j];
    }
  }
  __syncthreads();
  if (t < KA_RT * 10) {
    const int rr = t / 10, c = t - rr * 10;
    float s = 0.0f;
#pragma unroll
    for (int g = 0; g < 16; ++g) s += red[rr][g][c];
    bpart[((size_t)bq * R_ + (rbase + rr)) * C_ + c] = s;
  }
}

// ---------------------------------------------------------------------------
// k_bc: grid 80 = (c, r-slice/8). Every block redundantly computes the full
// softmax for its c; only rt==0 writes bvec_out (ping-pong, race-free).
// Tail: regen wb[r][c][o][i] = bf16(c[r,c]*W) for its (c, 144-r slice) —
// coalesced reads (512 B/r) and writes (256 B/r) in native layout.
// ---------------------------------------------------------------------------
__global__ __launch_bounds__(256) void k_bc(const float* __restrict__ bpart,
                                            const float* __restrict__ bvec_in,
                                            float* __restrict__ bvec_out,
                                            const float* __restrict__ W,
                                            unsigned short* __restrict__ wb,
                                            int first) {
  __shared__ float cl[R_];
  __shared__ float smx[4];
  __shared__ float sms[4];
  const int bx = blockIdx.x;
  const int c  = bx >> 3, rt = bx & 7;
  const int t  = threadIdx.x;
  float bv[5], ef[5];
  float mx = -3.402823466e38f;
#pragma unroll
  for (int k = 0; k < 5; ++k) {
    int r = t + k * 256;
    if (r < R_) {
      float s = bpart[(size_t)r * C_ + c]
              + bpart[((size_t)R_ + r) * C_ + c]
              + bpart[((size_t)2 * R_ + r) * C_ + c]
              + bpart[((size_t)3 * R_ + r) * C_ + c];
      float val = s * (1.0f / 256.0f);
      if (!first) val += bvec_in[r * C_ + c];
      if (rt == 0) bvec_out[r * C_ + c] = val;
      bv[k] = val;
      mx = fmaxf(mx, val);
    }
  }
  mx = fmaxf(mx, __shfl_xor(mx, 1));  mx = fmaxf(mx, __shfl_xor(mx, 2));
  mx = fmaxf(mx, __shfl_xor(mx, 4));  mx = fmaxf(mx, __shfl_xor(mx, 8));
  mx = fmaxf(mx, __shfl_xor(mx, 16)); mx = fmaxf(mx, __shfl_xor(mx, 32));
  if ((t & 63) == 0) smx[t >> 6] = mx;
  __syncthreads();
  const float MX = fmaxf(fmaxf(smx[0], smx[1]), fmaxf(smx[2], smx[3]));
  float se = 0.0f;
#pragma unroll
  for (int k = 0; k < 5; ++k) {
    int r = t + k * 256;
    if (r < R_) { ef[k] = expf(bv[k] - MX); se += ef[k]; }
  }
  se += __shfl_xor(se, 1);  se += __shfl_xor(se, 2);  se += __shfl_xor(se, 4);
  se += __shfl_xor(se, 8);  se += __shfl_xor(se, 16); se += __shfl_xor(se, 32);
  if ((t & 63) == 0) sms[t >> 6] = se;
  __syncthreads();
  const float inv = 1.0f / ((sms[0] + sms[1]) + (sms[2] + sms[3]));
#pragma unroll
  for (int k = 0; k < 5; ++k) {
    int r = t + k * 256;
    if (r < R_) cl[r] = ef[k] * inv;
  }
  __syncthreads();
  // regen wb for (c, r in [rt*144, rt*144+144)) — native layout, coalesced
  for (int idx = t; idx < 144 * 128; idx += 256) {
    const int r = rt * 144 + (idx >> 7), j = idx & 127;
    wb[((size_t)r * C_ + c) * 128 + j] =
        f2bf(W[(size_t)r * 1280 + c * 128 + j] * cl[r]);
  }
}

extern "C" void kernel_launch(void* const* d_in, const int* in_sizes, int n_in,
                              void* d_out, int out_size, void* d_ws, size_t ws_size,
                              hipStream_t stream) {
  const float* x = (const float*)d_in[0];  // (B,R,I) fp32
  const float* W = (const float*)d_in[1];  // (R,C,O,I) fp32
  float* out = (float*)d_out;              // (B,C,O,1) fp32
  float* ws = (float*)d_ws;

  float* partial = ws;                              // 16 * NV
  float* v      = partial + (size_t)GEMM_KS * NV;   // NV, [co][b]
  float* bvecA  = v + NV;
  float* bvecB  = bvecA + (R_ * C_);
  float* bpart  = bvecB + (R_ * C_);                // 4 * R * C
  unsigned short* xb = (unsigned short*)(bpart + 4 * R_ * C_);   // B*K bf16
  unsigned short* wb = xb + (size_t)B_ * K_;        // R*C*O*I bf16, native layout

  prep0<<<768, 256, 0, stream>>>(x, W, xb, wb);
  for (int it = 0; it < 3; ++it) {
    k_gemm<<<640, 256, 0, stream>>>(xb, wb, partial);
    k_sv<<<NV / 256, 256, 0, stream>>>(partial, (it == 2) ? out : v, it == 2 ? 1 : 0);
    if (it < 2) {
      k_a<<<KA_NSEG * 4, 256, 0, stream>>>(x, W, v, bpart);
      k_bc<<<80, 256, 0, stream>>>(bpart, bvecA, (it == 0) ? bvecA : bvecB,
                                   W, wb, it == 0 ? 1 : 0);
    }
  }
}